// Round 5
// baseline (532.108 us; speedup 1.0000x reference)
//
#include <hip/hip_runtime.h>
#include <math.h>

// ---------------------------------------------------------------------------
// NequIP fused, round 4: force A-fragment register residency.
//
// R3 post-mortem: VGPR_Count=92 proved the compiler rematerialized the A
// fragments from LDS inside every n-tile (16 ds_read_b128/tile/wave = 2x the
// B traffic on the LDS pipe + lgkmcnt before every MFMA pair) -> ~310us stall.
// This round:
//   - pin aR0/aR1 with opaque inline asm (non-rematerializable => resident)
//   - b2 staged to LDS (bz via ds_read; per-tile vmcnt covers only B prefetch)
//   - sEmb dropped (phase 2 reads emb via wave-uniform global loads) to keep
//     LDS at 77KB / 2 blocks/CU.
// ---------------------------------------------------------------------------

typedef __attribute__((ext_vector_type(8))) short s8v;    // 8 x bf16 (4 VGPR)
typedef __attribute__((ext_vector_type(4))) float f4v;    // 16x16 acc (4 f32)
typedef unsigned short ushort_t;
typedef unsigned int uint_t;

#define NTHR 256
#define TE 64
#define PINV(v) asm volatile("" : "+v"(v))

__device__ __forceinline__ ushort_t f2bf(float x) {
    uint_t u = __float_as_uint(x);
    u += 0x7fffu + ((u >> 16) & 1u);   // round-to-nearest-even
    return (ushort_t)(u >> 16);
}

// W2 [256][1024] fp32 -> W2bf [1024][256] bf16 (transposed, k-contiguous).
__global__ void conv_w2(const float* __restrict__ W2, ushort_t* __restrict__ W2bf) {
    int idx = blockIdx.x * 256 + threadIdx.x;      // 65536 threads, 4 k each
    int n  = idx & 1023;
    int k4 = (idx >> 10) << 2;
    uint_t lo = (uint_t)f2bf(W2[(size_t)(k4 + 0) * 1024 + n]) |
                ((uint_t)f2bf(W2[(size_t)(k4 + 1) * 1024 + n]) << 16);
    uint_t hi = (uint_t)f2bf(W2[(size_t)(k4 + 2) * 1024 + n]) |
                ((uint_t)f2bf(W2[(size_t)(k4 + 3) * 1024 + n]) << 16);
    ((uint2*)W2bf)[(n * 256 + k4) >> 2] = make_uint2(lo, hi);
}

// ---------------- CSR build ----------------
__global__ void hist_kernel(const int* __restrict__ edst, int* __restrict__ counts, int E) {
    int i = blockIdx.x * 256 + threadIdx.x;
    if (i < E) atomicAdd(&counts[edst[i]], 1);
}

__global__ __launch_bounds__(1024)
void scan_kernel(const int* __restrict__ counts, int* __restrict__ offsets, int N) {
    __shared__ int sdata[1024];
    const int t = threadIdx.x;
    const int C = (N + 1023) / 1024;
    const int lo = t * C;
    const int hi = min(lo + C, N);
    int sum = 0;
    for (int i = lo; i < hi; ++i) sum += counts[i];
    sdata[t] = sum;
    __syncthreads();
    for (int s = 1; s < 1024; s <<= 1) {
        int v = (t >= s) ? sdata[t - s] : 0;
        __syncthreads();
        sdata[t] += v;
        __syncthreads();
    }
    int run = sdata[t] - sum;
    for (int i = lo; i < hi; ++i) { offsets[i] = run; run += counts[i]; }
    if (t == 1023) offsets[N] = run;
}

__global__ void fill_kernel(const int* __restrict__ edst,
                            const int* __restrict__ offsets,
                            int* __restrict__ cursor,
                            int* __restrict__ elist, int E) {
    int i = blockIdx.x * 256 + threadIdx.x;
    if (i < E) {
        int d = edst[i];
        int pos = offsets[d] + atomicAdd(&cursor[d], 1);
        elist[pos] = i;
    }
}

// ---------------- gather: one wave per node ----------------
__global__ __launch_bounds__(256)
void gather_kernel(const float* __restrict__ F,
                   const int* __restrict__ offsets,
                   const int* __restrict__ elist,
                   float* __restrict__ out, int N) {
    const int lane = threadIdx.x & 63;
    const int node = (blockIdx.x * 256 + threadIdx.x) >> 6;
    if (node >= N) return;
    const int base = offsets[node];
    const int end  = offsets[node + 1];
    float acc = 0.f;
    for (int j0 = base; j0 < end; j0 += 64) {
        const int rem = min(64, end - j0);
        int myeid = (lane < rem) ? elist[j0 + lane] : 0;
        int j = 0;
        for (; j + 4 <= rem; j += 4) {
            const int a0 = __shfl(myeid, j    );
            const int a1 = __shfl(myeid, j + 1);
            const int a2 = __shfl(myeid, j + 2);
            const int a3 = __shfl(myeid, j + 3);
            const float r0 = F[(size_t)a0 * 64 + lane];
            const float r1 = F[(size_t)a1 * 64 + lane];
            const float r2 = F[(size_t)a2 * 64 + lane];
            const float r3 = F[(size_t)a3 * 64 + lane];
            acc += (r0 + r1) + (r2 + r3);
        }
        for (; j < rem; ++j) {
            const int a = __shfl(myeid, j);
            acc += F[(size_t)a * 64 + lane];
        }
    }
    out[(size_t)node * 64 + lane] = acc;
}

// ---------------- main fused edge kernel ----------------
__global__ __launch_bounds__(NTHR, 2)
void nequip_mfma(const float* __restrict__ nodef,
                 const float* __restrict__ eattr,
                 const float* __restrict__ eemb,
                 const float* __restrict__ W1,
                 const float* __restrict__ b1,
                 const ushort_t* __restrict__ W2bf,
                 const float* __restrict__ b2,
                 const int* __restrict__ esrc,
                 float* __restrict__ F,
                 int E, float CC)
{
    __shared__ __align__(16) ushort_t sAu[TE * 256];   // 32 KB h bf16, A-frag order
    __shared__ __align__(16) float sB2[1024];          // 4 KB  b2 bias
    __shared__ __align__(16) float sCss[16 * 64];      // coef[i][e] = CC*y0*s
    __shared__ __align__(16) float sCvv[16 * 64];      // CC/sqrt3*(y1.v)
    __shared__ __align__(16) float sCsv[16 * 64];      // CC*s
    __shared__ __align__(16) float sCvs[48 * 64];      // [(i*3+a)][e] = CC*y0*v
    __shared__ __align__(16) float sAttrT[4 * 64];     // [c][e]
    __shared__ __align__(16) float resS[64 * 16];      // single-owner, no init
    __shared__ __align__(16) float resV[64 * 48];      // single-owner, no init

    const int t  = threadIdx.x;
    const int e0 = blockIdx.x * TE;

    // ---------------- phase 1: staging + coef tables ----------------
    ((float4*)sB2)[t] = ((const float4*)b2)[t];        // 256 x float4 = 1024 f
    if (t < TE) {
        int ge = e0 + t;
        float4 a = make_float4(0.f, 0.f, 0.f, 0.f);
        if (ge < E) a = *(const float4*)(eattr + (size_t)ge * 4);
        sAttrT[0 * 64 + t] = a.x; sAttrT[1 * 64 + t] = a.y;
        sAttrT[2 * 64 + t] = a.z; sAttrT[3 * 64 + t] = a.w;
    }
    {   // thread t -> edge e = t>>2, i-quad iq = t&3
        const int e = t >> 2, iq = t & 3;
        const int ge = e0 + e;
        const bool ok = ge < E;
        float y0 = 0.f, y1x = 0.f, y1y = 0.f, y1z = 0.f;
        int src = 0;
        if (ok) {
            float4 a = *(const float4*)(eattr + (size_t)ge * 4);
            y0 = a.x; y1x = a.y; y1y = a.z; y1z = a.w;
            src = esrc[ge];
        }
        const float* xp = nodef + (size_t)src * 64;
        float4 z = make_float4(0.f, 0.f, 0.f, 0.f);
        float4 sv = ok ? *(const float4*)(xp + iq * 4) : z;
        float4 v0 = ok ? *(const float4*)(xp + 16 + iq * 12) : z;
        float4 v1 = ok ? *(const float4*)(xp + 16 + iq * 12 + 4) : z;
        float4 v2 = ok ? *(const float4*)(xp + 16 + iq * 12 + 8) : z;
        const float K3 = CC * 0.57735026918962576f;   // CC/sqrt(3)
        float sarr[4] = { sv.x, sv.y, sv.z, sv.w };
        float varr[12] = { v0.x, v0.y, v0.z, v0.w, v1.x, v1.y, v1.z, v1.w,
                           v2.x, v2.y, v2.z, v2.w };
        #pragma unroll
        for (int j = 0; j < 4; ++j) {
            const int i = iq * 4 + j;
            const float s  = sarr[j];
            const float vx = varr[j * 3 + 0], vy = varr[j * 3 + 1], vz = varr[j * 3 + 2];
            sCss[i * 64 + e] = CC * y0 * s;
            sCvv[i * 64 + e] = K3 * (y1x * vx + y1y * vy + y1z * vz);
            sCsv[i * 64 + e] = CC * s;
            sCvs[(i * 3 + 0) * 64 + e] = CC * y0 * vx;
            sCvs[(i * 3 + 1) * 64 + e] = CC * y0 * vy;
            sCvs[(i * 3 + 2) * 64 + e] = CC * y0 * vz;
        }
    }

    // ---- phase 2: h = silu(emb@W1+b1) -> sAu, 16x16x32 A-frag order ----
    // element (e,k): kk=k>>5, lane=(e&15)+16*((k>>3)&3), slot=k&7; lane^kk swizzle
    {
        const int p = t & 127;         // column pair p -> cols 2p, 2p+1
        const int ehalf = t >> 7;
        const int n0 = 2 * p;
        float w1a[18], w1b[18];
        #pragma unroll
        for (int m = 0; m < 18; ++m) {
            float2 wv = *(const float2*)(W1 + m * 256 + n0);
            w1a[m] = wv.x; w1b[m] = wv.y;
        }
        const float2 bv = *(const float2*)(b1 + n0);
        const int kk = p >> 4;                       // k-iter (0..7)
        const int lhi = 16 * ((p >> 2) & 3);
        const int wsub = p & 3;                      // uint slot within 16B frag
        uint_t* sA32 = (uint_t*)sAu;
        for (int er = 0; er < 32; ++er) {
            const int e = ehalf * 32 + er;
            const int ge = e0 + e;
            const float* ep = eemb + (size_t)ge * 18;   // wave-uniform address
            float a0 = bv.x, a1 = bv.y;
            #pragma unroll
            for (int m = 0; m < 18; ++m) {
                const float em = (ge < E) ? ep[m] : 0.f;
                a0 = fmaf(em, w1a[m], a0);
                a1 = fmaf(em, w1b[m], a1);
            }
            a0 = a0 / (1.f + __expf(-a0));          // silu
            a1 = a1 / (1.f + __expf(-a1));
            const uint_t pk = (uint_t)f2bf(a0) | ((uint_t)f2bf(a1) << 16);
            const int lane_sw = ((e & 15) + lhi) ^ kk;
            sA32[(((e >> 4) * 8 + kk) * 64 + lane_sw) * 4 + wsub] = pk;
        }
    }
    __syncthreads();

    // ---------------- phase 3: per-wave n-tile loop ----------------
    const int lane  = t & 63;
    const int w     = t >> 6;
    const int mhalf = w & 1;          // e-half: e in [mhalf*32, +32)
    const int rpair = w >> 1;         // slabs {2rpair, 2rpair+1}
    const int jj    = lane & 15;      // output col j
    const int q4    = lane >> 4;
    const int eb0   = mhalf * 32 + q4 * 4;   // e-base of acc regs, m-tile 0
    const int eb1   = eb0 + 16;              //                     m-tile 1
    const int r0    = rpair * 2;

    // A preload: 2 m-tiles x 8 kk (64 VGPRs), PINNED so regalloc cannot
    // rematerialize them from LDS inside the tile loop (R3's stall).
    s8v aR0[8], aR1[8];
    #pragma unroll
    for (int kk = 0; kk < 8; ++kk) {
        aR0[kk] = *(const s8v*)(sAu + (((mhalf * 2 + 0) * 8 + kk) * 64 + (lane ^ kk)) * 8);
        aR1[kk] = *(const s8v*)(sAu + (((mhalf * 2 + 1) * 8 + kk) * 64 + (lane ^ kk)) * 8);
    }
    #pragma unroll
    for (int kk = 0; kk < 8; ++kk) { PINV(aR0[kk]); PINV(aR1[kk]); }

    const ushort_t* Bl = W2bf + (size_t)jj * 256 + q4 * 8;  // + nb*256 + kk*32

    if (rpair == 0) {
        float pS0[4] = {0.f, 0.f, 0.f, 0.f}, pS1[4] = {0.f, 0.f, 0.f, 0.f};
        s8v bc[8];
        {
            const int nb = r0 * 256;
            #pragma unroll
            for (int kk = 0; kk < 8; ++kk) bc[kk] = *(const s8v*)(Bl + (size_t)nb * 256 + kk * 32);
        }
        float bz = sB2[r0 * 256 + jj];
        #pragma unroll 1
        for (int ti = 0; ti < 32; ++ti) {
            const int tiN = (ti < 31) ? ti + 1 : 31;
            const int nbN = (r0 + (tiN >> 4)) * 256 + (tiN & 15) * 16;
            const float bzN = sB2[nbN + jj];
            f4v acc0; acc0[0] = bz; acc0[1] = bz; acc0[2] = bz; acc0[3] = bz;
            f4v acc1 = acc0;
            s8v bn[8];
            #pragma unroll
            for (int kk = 0; kk < 8; ++kk) {
                bn[kk] = *(const s8v*)(Bl + (size_t)nbN * 256 + kk * 32);
                acc0 = __builtin_amdgcn_mfma_f32_16x16x32_bf16(aR0[kk], bc[kk], acc0, 0, 0, 0);
                acc1 = __builtin_amdgcn_mfma_f32_16x16x32_bf16(aR1[kk], bc[kk], acc1, 0, 0, 0);
            }
            const int i = ti & 15;
            const float* C = (ti < 16) ? sCss : sCvv;
            const float4 c0 = *(const float4*)(C + i * 64 + eb0);
            const float4 c1 = *(const float4*)(C + i * 64 + eb1);
            pS0[0] = fmaf(c0.x, acc0[0], pS0[0]); pS0[1] = fmaf(c0.y, acc0[1], pS0[1]);
            pS0[2] = fmaf(c0.z, acc0[2], pS0[2]); pS0[3] = fmaf(c0.w, acc0[3], pS0[3]);
            pS1[0] = fmaf(c1.x, acc1[0], pS1[0]); pS1[1] = fmaf(c1.y, acc1[1], pS1[1]);
            pS1[2] = fmaf(c1.z, acc1[2], pS1[2]); pS1[3] = fmaf(c1.w, acc1[3], pS1[3]);
            #pragma unroll
            for (int kk = 0; kk < 8; ++kk) bc[kk] = bn[kk];
            bz = bzN;
        }
        #pragma unroll
        for (int q = 0; q < 4; ++q) {
            resS[(eb0 + q) * 16 + jj] = pS0[q];
            resS[(eb1 + q) * 16 + jj] = pS1[q];
        }
    } else {
        float pSV0[4] = {0.f, 0.f, 0.f, 0.f}, pSV1[4] = {0.f, 0.f, 0.f, 0.f};
        float pVS0[3][4] = {{0.f}}, pVS1[3][4] = {{0.f}};
        s8v bc[8];
        {
            const int nb = r0 * 256;
            #pragma unroll
            for (int kk = 0; kk < 8; ++kk) bc[kk] = *(const s8v*)(Bl + (size_t)nb * 256 + kk * 32);
        }
        float bz = sB2[r0 * 256 + jj];
        #pragma unroll 1
        for (int ti = 0; ti < 32; ++ti) {
            const int tiN = (ti < 31) ? ti + 1 : 31;
            const int nbN = (r0 + (tiN >> 4)) * 256 + (tiN & 15) * 16;
            const float bzN = sB2[nbN + jj];
            f4v acc0; acc0[0] = bz; acc0[1] = bz; acc0[2] = bz; acc0[3] = bz;
            f4v acc1 = acc0;
            s8v bn[8];
            #pragma unroll
            for (int kk = 0; kk < 8; ++kk) {
                bn[kk] = *(const s8v*)(Bl + (size_t)nbN * 256 + kk * 32);
                acc0 = __builtin_amdgcn_mfma_f32_16x16x32_bf16(aR0[kk], bc[kk], acc0, 0, 0, 0);
                acc1 = __builtin_amdgcn_mfma_f32_16x16x32_bf16(aR1[kk], bc[kk], acc1, 0, 0, 0);
            }
            const int i = ti & 15;
            if (ti < 16) {   // slab sv
                const float4 c0 = *(const float4*)(sCsv + i * 64 + eb0);
                const float4 c1 = *(const float4*)(sCsv + i * 64 + eb1);
                pSV0[0] = fmaf(c0.x, acc0[0], pSV0[0]); pSV0[1] = fmaf(c0.y, acc0[1], pSV0[1]);
                pSV0[2] = fmaf(c0.z, acc0[2], pSV0[2]); pSV0[3] = fmaf(c0.w, acc0[3], pSV0[3]);
                pSV1[0] = fmaf(c1.x, acc1[0], pSV1[0]); pSV1[1] = fmaf(c1.y, acc1[1], pSV1[1]);
                pSV1[2] = fmaf(c1.z, acc1[2], pSV1[2]); pSV1[3] = fmaf(c1.w, acc1[3], pSV1[3]);
            } else {          // slab vs
                #pragma unroll
                for (int a = 0; a < 3; ++a) {
                    const float4 c0 = *(const float4*)(sCvs + (i * 3 + a) * 64 + eb0);
                    const float4 c1 = *(const float4*)(sCvs + (i * 3 + a) * 64 + eb1);
                    pVS0[a][0] = fmaf(c0.x, acc0[0], pVS0[a][0]);
                    pVS0[a][1] = fmaf(c0.y, acc0[1], pVS0[a][1]);
                    pVS0[a][2] = fmaf(c0.z, acc0[2], pVS0[a][2]);
                    pVS0[a][3] = fmaf(c0.w, acc0[3], pVS0[a][3]);
                    pVS1[a][0] = fmaf(c1.x, acc1[0], pVS1[a][0]);
                    pVS1[a][1] = fmaf(c1.y, acc1[1], pVS1[a][1]);
                    pVS1[a][2] = fmaf(c1.z, acc1[2], pVS1[a][2]);
                    pVS1[a][3] = fmaf(c1.w, acc1[3], pVS1[a][3]);
                }
            }
            #pragma unroll
            for (int kk = 0; kk < 8; ++kk) bc[kk] = bn[kk];
            bz = bzN;
        }
        // out_v[e][j][a] = y1[a][e]*pSV + pVS[a]   (scales folded in coefs)
        #pragma unroll
        for (int a = 0; a < 3; ++a) {
            const float4 y0q = *(const float4*)(sAttrT + (1 + a) * 64 + eb0);
            const float4 y1q = *(const float4*)(sAttrT + (1 + a) * 64 + eb1);
            #pragma unroll
            for (int q = 0; q < 4; ++q) {
                resV[(eb0 + q) * 48 + jj * 3 + a] =
                    fmaf(((const float*)&y0q)[q], pSV0[q], pVS0[a][q]);
                resV[(eb1 + q) * 48 + jj * 3 + a] =
                    fmaf(((const float*)&y1q)[q], pSV1[q], pVS1[a][q]);
            }
        }
    }
    __syncthreads();

    // ---------------- phase 4: coalesced store to F[e][64] ----------------
    {
        const int e = t >> 2, qq = t & 3;
        const int ge = e0 + e;
        if (ge < E) {
            float* fp = F + (size_t)ge * 64 + qq * 16;
            const float* rp = (qq == 0) ? (resS + e * 16) : (resV + e * 48 + (qq - 1) * 16);
            #pragma unroll
            for (int c = 0; c < 16; c += 4)
                *(float4*)(fp + c) = *(const float4*)(rp + c);
        }
    }
}

extern "C" void kernel_launch(void* const* d_in, const int* in_sizes, int n_in,
                              void* d_out, int out_size, void* d_ws, size_t ws_size,
                              hipStream_t stream)
{
    const float* node_features = (const float*)d_in[0];
    const float* edge_attr     = (const float*)d_in[1];
    const float* edge_emb      = (const float*)d_in[2];
    const float* W1            = (const float*)d_in[3];
    const float* b1            = (const float*)d_in[4];
    const float* W2            = (const float*)d_in[5];
    const float* b2            = (const float*)d_in[6];
    const int*   edge_src      = (const int*)d_in[7];
    const int*   edge_dst      = (const int*)d_in[8];
    float*       out           = (float*)d_out;

    const int E = in_sizes[7];
    const int N = out_size / 64;
    const float num_neigh = (float)E / (float)N;
    const float CC = 0.17677669529663689f / sqrtf(num_neigh);

    // ---- workspace layout ----
    char* ws = (char*)d_ws;
    size_t off = 0;
    auto alloc = [&](size_t bytes) { char* p = ws + off; off = (off + bytes + 255) & ~(size_t)255; return p; };
    ushort_t* W2bf   = (ushort_t*)alloc((size_t)1024 * 256 * 2);
    int*      counts = (int*)alloc((size_t)N * 4);
    int*      offs   = (int*)alloc((size_t)(N + 1) * 4);
    int*      cursor = (int*)alloc((size_t)N * 4);
    int*      elist  = (int*)alloc((size_t)E * 4);
    float*    F      = (float*)alloc((size_t)E * 64 * 4);
    (void)ws_size;

    hipMemsetAsync(counts, 0, (size_t)N * 4, stream);
    hipMemsetAsync(cursor, 0, (size_t)N * 4, stream);

    conv_w2<<<256, 256, 0, stream>>>(W2, W2bf);
    hist_kernel<<<(E + 255) / 256, 256, 0, stream>>>(edge_dst, counts, E);
    scan_kernel<<<1, 1024, 0, stream>>>(counts, offs, N);
    fill_kernel<<<(E + 255) / 256, 256, 0, stream>>>(edge_dst, offs, cursor, elist, E);

    const int blocks = (E + TE - 1) / TE;
    nequip_mfma<<<blocks, NTHR, 0, stream>>>(
        node_features, edge_attr, edge_emb, W1, b1, W2bf, b2,
        edge_src, F, E, CC);

    gather_kernel<<<(N + 3) / 4, 256, 0, stream>>>(F, offs, elist, out, N);
}

// Round 6
// 472.457 us; speedup vs baseline: 1.1263x; 1.1263x over previous
//
#include <hip/hip_runtime.h>
#include <math.h>

// ---------------------------------------------------------------------------
// NequIP fused, round 5: fix the register-pressure TARGET, not the symptom.
//
// R4/R5 post-mortem: VGPR_Count stayed 92 through the asm-pin attempt -> the
// scheduler's pressure target (set by achievable-occupancy heuristic) made it
// rematerialize A-fragments from LDS every n-tile (16 ds_read_b128/tile ~192cy
// vs 77cy MFMA). LDS caps us at 2 blocks/CU anyway, so declare it:
// amdgpu_waves_per_eu(2,2) => VGPR budget 256, A (64 regs) stays resident.
// Also: revert phase2 to LDS sEmb (R5's global reads regressed), restore sB2
// via LDS aliasing (sEmb dead after phase2; res written after the barrier).
// ---------------------------------------------------------------------------

typedef __attribute__((ext_vector_type(8))) short s8v;    // 8 x bf16 (4 VGPR)
typedef __attribute__((ext_vector_type(4))) float f4v;    // 16x16 acc (4 f32)
typedef unsigned short ushort_t;
typedef unsigned int uint_t;

#define NTHR 256
#define TE 64

__device__ __forceinline__ ushort_t f2bf(float x) {
    uint_t u = __float_as_uint(x);
    u += 0x7fffu + ((u >> 16) & 1u);   // round-to-nearest-even
    return (ushort_t)(u >> 16);
}

// W2 [256][1024] fp32 -> W2bf [1024][256] bf16 (transposed, k-contiguous).
__global__ void conv_w2(const float* __restrict__ W2, ushort_t* __restrict__ W2bf) {
    int idx = blockIdx.x * 256 + threadIdx.x;      // 65536 threads, 4 k each
    int n  = idx & 1023;
    int k4 = (idx >> 10) << 2;
    uint_t lo = (uint_t)f2bf(W2[(size_t)(k4 + 0) * 1024 + n]) |
                ((uint_t)f2bf(W2[(size_t)(k4 + 1) * 1024 + n]) << 16);
    uint_t hi = (uint_t)f2bf(W2[(size_t)(k4 + 2) * 1024 + n]) |
                ((uint_t)f2bf(W2[(size_t)(k4 + 3) * 1024 + n]) << 16);
    ((uint2*)W2bf)[(n * 256 + k4) >> 2] = make_uint2(lo, hi);
}

// ---------------- CSR build ----------------
__global__ void hist_kernel(const int* __restrict__ edst, int* __restrict__ counts, int E) {
    int i = blockIdx.x * 256 + threadIdx.x;
    if (i < E) atomicAdd(&counts[edst[i]], 1);
}

__global__ __launch_bounds__(1024)
void scan_kernel(const int* __restrict__ counts, int* __restrict__ offsets, int N) {
    __shared__ int sdata[1024];
    const int t = threadIdx.x;
    const int C = (N + 1023) / 1024;
    const int lo = t * C;
    const int hi = min(lo + C, N);
    int sum = 0;
    for (int i = lo; i < hi; ++i) sum += counts[i];
    sdata[t] = sum;
    __syncthreads();
    for (int s = 1; s < 1024; s <<= 1) {
        int v = (t >= s) ? sdata[t - s] : 0;
        __syncthreads();
        sdata[t] += v;
        __syncthreads();
    }
    int run = sdata[t] - sum;
    for (int i = lo; i < hi; ++i) { offsets[i] = run; run += counts[i]; }
    if (t == 1023) offsets[N] = run;
}

__global__ void fill_kernel(const int* __restrict__ edst,
                            const int* __restrict__ offsets,
                            int* __restrict__ cursor,
                            int* __restrict__ elist, int E) {
    int i = blockIdx.x * 256 + threadIdx.x;
    if (i < E) {
        int d = edst[i];
        int pos = offsets[d] + atomicAdd(&cursor[d], 1);
        elist[pos] = i;
    }
}

// ---------------- gather: one wave per node ----------------
__global__ __launch_bounds__(256)
void gather_kernel(const float* __restrict__ F,
                   const int* __restrict__ offsets,
                   const int* __restrict__ elist,
                   float* __restrict__ out, int N) {
    const int lane = threadIdx.x & 63;
    const int node = (blockIdx.x * 256 + threadIdx.x) >> 6;
    if (node >= N) return;
    const int base = offsets[node];
    const int end  = offsets[node + 1];
    float acc = 0.f;
    for (int j0 = base; j0 < end; j0 += 64) {
        const int rem = min(64, end - j0);
        int myeid = (lane < rem) ? elist[j0 + lane] : 0;
        int j = 0;
        for (; j + 4 <= rem; j += 4) {
            const int a0 = __shfl(myeid, j    );
            const int a1 = __shfl(myeid, j + 1);
            const int a2 = __shfl(myeid, j + 2);
            const int a3 = __shfl(myeid, j + 3);
            const float r0 = F[(size_t)a0 * 64 + lane];
            const float r1 = F[(size_t)a1 * 64 + lane];
            const float r2 = F[(size_t)a2 * 64 + lane];
            const float r3 = F[(size_t)a3 * 64 + lane];
            acc += (r0 + r1) + (r2 + r3);
        }
        for (; j < rem; ++j) {
            const int a = __shfl(myeid, j);
            acc += F[(size_t)a * 64 + lane];
        }
    }
    out[(size_t)node * 64 + lane] = acc;
}

// ---------------- main fused edge kernel ----------------
// waves_per_eu(2,2): LDS (78.8KB) caps us at 2 blocks/CU = 2 waves/EU anyway;
// telling the compiler raises its VGPR budget to 256 so the A fragments
// (64 VGPRs) stay resident instead of being rematerialized from LDS per tile.
__global__ __attribute__((amdgpu_flat_work_group_size(NTHR, NTHR),
                          amdgpu_waves_per_eu(2, 2)))
void nequip_mfma(const float* __restrict__ nodef,
                 const float* __restrict__ eattr,
                 const float* __restrict__ eemb,
                 const float* __restrict__ W1,
                 const float* __restrict__ b1,
                 const ushort_t* __restrict__ W2bf,
                 const float* __restrict__ b2,
                 const int* __restrict__ esrc,
                 float* __restrict__ F,
                 int E, float CC)
{
    __shared__ __align__(16) ushort_t sAu[TE * 256];   // 32 KB h bf16, A-frag order
    __shared__ __align__(16) float sB2[1024];          // 4 KB  b2 bias
    __shared__ __align__(16) float sCss[16 * 64];      // coef[i][e] = CC*y0*s
    __shared__ __align__(16) float sCvv[16 * 64];      // CC/sqrt3*(y1.v)
    __shared__ __align__(16) float sCsv[16 * 64];      // CC*s
    __shared__ __align__(16) float sCvs[48 * 64];      // [(i*3+a)][e] = CC*y0*v
    __shared__ __align__(16) float sAttrT[4 * 64];     // [c][e]
    __shared__ __align__(16) float sRes[64 * 64];      // 16 KB: sEmb (ph1-2) then resS|resV (ph3-4)

    float* sEmb = sRes;                 // 64*18 floats, dead after phase 2
    float* resS = sRes;                 // 64*16, written after ph2->3 barrier
    float* resV = sRes + 64 * 16;       // 64*48

    const int t  = threadIdx.x;
    const int e0 = blockIdx.x * TE;

    // ---------------- phase 1: staging + coef tables ----------------
    ((float4*)sB2)[t] = ((const float4*)b2)[t];        // 256 x float4 = 1024 f
    for (int idx = t; idx < TE * 18; idx += NTHR) {
        size_t g = (size_t)e0 * 18 + idx;
        sEmb[idx] = (g < (size_t)E * 18) ? eemb[g] : 0.f;
    }
    if (t < TE) {
        int ge = e0 + t;
        float4 a = make_float4(0.f, 0.f, 0.f, 0.f);
        if (ge < E) a = *(const float4*)(eattr + (size_t)ge * 4);
        sAttrT[0 * 64 + t] = a.x; sAttrT[1 * 64 + t] = a.y;
        sAttrT[2 * 64 + t] = a.z; sAttrT[3 * 64 + t] = a.w;
    }
    {   // thread t -> edge e = t>>2, i-quad iq = t&3
        const int e = t >> 2, iq = t & 3;
        const int ge = e0 + e;
        const bool ok = ge < E;
        float y0 = 0.f, y1x = 0.f, y1y = 0.f, y1z = 0.f;
        int src = 0;
        if (ok) {
            float4 a = *(const float4*)(eattr + (size_t)ge * 4);
            y0 = a.x; y1x = a.y; y1y = a.z; y1z = a.w;
            src = esrc[ge];
        }
        const float* xp = nodef + (size_t)src * 64;
        float4 z = make_float4(0.f, 0.f, 0.f, 0.f);
        float4 sv = ok ? *(const float4*)(xp + iq * 4) : z;
        float4 v0 = ok ? *(const float4*)(xp + 16 + iq * 12) : z;
        float4 v1 = ok ? *(const float4*)(xp + 16 + iq * 12 + 4) : z;
        float4 v2 = ok ? *(const float4*)(xp + 16 + iq * 12 + 8) : z;
        const float K3 = CC * 0.57735026918962576f;   // CC/sqrt(3)
        float sarr[4] = { sv.x, sv.y, sv.z, sv.w };
        float varr[12] = { v0.x, v0.y, v0.z, v0.w, v1.x, v1.y, v1.z, v1.w,
                           v2.x, v2.y, v2.z, v2.w };
        #pragma unroll
        for (int j = 0; j < 4; ++j) {
            const int i = iq * 4 + j;
            const float s  = sarr[j];
            const float vx = varr[j * 3 + 0], vy = varr[j * 3 + 1], vz = varr[j * 3 + 2];
            sCss[i * 64 + e] = CC * y0 * s;
            sCvv[i * 64 + e] = K3 * (y1x * vx + y1y * vy + y1z * vz);
            sCsv[i * 64 + e] = CC * s;
            sCvs[(i * 3 + 0) * 64 + e] = CC * y0 * vx;
            sCvs[(i * 3 + 1) * 64 + e] = CC * y0 * vy;
            sCvs[(i * 3 + 2) * 64 + e] = CC * y0 * vz;
        }
    }
    __syncthreads();

    // ---- phase 2: h = silu(emb@W1+b1) -> sAu, 16x16x32 A-frag order ----
    // element (e,k): kk=k>>5, lane=(e&15)+16*((k>>3)&3), slot=k&7; lane^kk swizzle
    {
        const int p = t & 127;         // column pair p -> cols 2p, 2p+1
        const int ehalf = t >> 7;
        const int n0 = 2 * p;
        float w1a[18], w1b[18];
        #pragma unroll
        for (int m = 0; m < 18; ++m) {
            float2 wv = *(const float2*)(W1 + m * 256 + n0);
            w1a[m] = wv.x; w1b[m] = wv.y;
        }
        const float2 bv = *(const float2*)(b1 + n0);
        const int kk = p >> 4;                       // k-iter (0..7)
        const int lhi = 16 * ((p >> 2) & 3);
        const int wsub = p & 3;                      // uint slot within 16B frag
        uint_t* sA32 = (uint_t*)sAu;
        for (int er = 0; er < 32; ++er) {
            const int e = ehalf * 32 + er;
            float a0 = bv.x, a1 = bv.y;
            const float* ep = sEmb + e * 18;
            #pragma unroll
            for (int m = 0; m < 18; ++m) {
                const float em = ep[m];
                a0 = fmaf(em, w1a[m], a0);
                a1 = fmaf(em, w1b[m], a1);
            }
            a0 = a0 / (1.f + __expf(-a0));          // silu
            a1 = a1 / (1.f + __expf(-a1));
            const uint_t pk = (uint_t)f2bf(a0) | ((uint_t)f2bf(a1) << 16);
            const int lane_sw = ((e & 15) + lhi) ^ kk;
            sA32[(((e >> 4) * 8 + kk) * 64 + lane_sw) * 4 + wsub] = pk;
        }
    }
    __syncthreads();

    // ---------------- phase 3: per-wave n-tile loop ----------------
    const int lane  = t & 63;
    const int w     = t >> 6;
    const int mhalf = w & 1;          // e-half: e in [mhalf*32, +32)
    const int rpair = w >> 1;         // slabs {2rpair, 2rpair+1}
    const int jj    = lane & 15;      // output col j
    const int q4    = lane >> 4;
    const int eb0   = mhalf * 32 + q4 * 4;   // e-base of acc regs, m-tile 0
    const int eb1   = eb0 + 16;              //                     m-tile 1
    const int r0    = rpair * 2;

    // A preload: 2 m-tiles x 8 kk (64 VGPRs) — resident under waves_per_eu(2,2)
    s8v aR0[8], aR1[8];
    #pragma unroll
    for (int kk = 0; kk < 8; ++kk) {
        aR0[kk] = *(const s8v*)(sAu + (((mhalf * 2 + 0) * 8 + kk) * 64 + (lane ^ kk)) * 8);
        aR1[kk] = *(const s8v*)(sAu + (((mhalf * 2 + 1) * 8 + kk) * 64 + (lane ^ kk)) * 8);
    }

    const ushort_t* Bl = W2bf + (size_t)jj * 256 + q4 * 8;  // + nb*256 + kk*32

    if (rpair == 0) {
        float pS0[4] = {0.f, 0.f, 0.f, 0.f}, pS1[4] = {0.f, 0.f, 0.f, 0.f};
        s8v bc[8];
        {
            const int nb = r0 * 256;
            #pragma unroll
            for (int kk = 0; kk < 8; ++kk) bc[kk] = *(const s8v*)(Bl + (size_t)nb * 256 + kk * 32);
        }
        float bz = sB2[r0 * 256 + jj];
        #pragma unroll 1
        for (int ti = 0; ti < 32; ++ti) {
            const int tiN = (ti < 31) ? ti + 1 : 31;
            const int nbN = (r0 + (tiN >> 4)) * 256 + (tiN & 15) * 16;
            const float bzN = sB2[nbN + jj];
            f4v acc0; acc0[0] = bz; acc0[1] = bz; acc0[2] = bz; acc0[3] = bz;
            f4v acc1 = acc0;
            s8v bn[8];
            #pragma unroll
            for (int kk = 0; kk < 8; ++kk) {
                bn[kk] = *(const s8v*)(Bl + (size_t)nbN * 256 + kk * 32);
                acc0 = __builtin_amdgcn_mfma_f32_16x16x32_bf16(aR0[kk], bc[kk], acc0, 0, 0, 0);
                acc1 = __builtin_amdgcn_mfma_f32_16x16x32_bf16(aR1[kk], bc[kk], acc1, 0, 0, 0);
            }
            const int i = ti & 15;
            const float* C = (ti < 16) ? sCss : sCvv;
            const float4 c0 = *(const float4*)(C + i * 64 + eb0);
            const float4 c1 = *(const float4*)(C + i * 64 + eb1);
            pS0[0] = fmaf(c0.x, acc0[0], pS0[0]); pS0[1] = fmaf(c0.y, acc0[1], pS0[1]);
            pS0[2] = fmaf(c0.z, acc0[2], pS0[2]); pS0[3] = fmaf(c0.w, acc0[3], pS0[3]);
            pS1[0] = fmaf(c1.x, acc1[0], pS1[0]); pS1[1] = fmaf(c1.y, acc1[1], pS1[1]);
            pS1[2] = fmaf(c1.z, acc1[2], pS1[2]); pS1[3] = fmaf(c1.w, acc1[3], pS1[3]);
            #pragma unroll
            for (int kk = 0; kk < 8; ++kk) bc[kk] = bn[kk];
            bz = bzN;
        }
        #pragma unroll
        for (int q = 0; q < 4; ++q) {
            resS[(eb0 + q) * 16 + jj] = pS0[q];
            resS[(eb1 + q) * 16 + jj] = pS1[q];
        }
    } else {
        float pSV0[4] = {0.f, 0.f, 0.f, 0.f}, pSV1[4] = {0.f, 0.f, 0.f, 0.f};
        float pVS0[3][4] = {{0.f}}, pVS1[3][4] = {{0.f}};
        s8v bc[8];
        {
            const int nb = r0 * 256;
            #pragma unroll
            for (int kk = 0; kk < 8; ++kk) bc[kk] = *(const s8v*)(Bl + (size_t)nb * 256 + kk * 32);
        }
        float bz = sB2[r0 * 256 + jj];
        #pragma unroll 1
        for (int ti = 0; ti < 32; ++ti) {
            const int tiN = (ti < 31) ? ti + 1 : 31;
            const int nbN = (r0 + (tiN >> 4)) * 256 + (tiN & 15) * 16;
            const float bzN = sB2[nbN + jj];
            f4v acc0; acc0[0] = bz; acc0[1] = bz; acc0[2] = bz; acc0[3] = bz;
            f4v acc1 = acc0;
            s8v bn[8];
            #pragma unroll
            for (int kk = 0; kk < 8; ++kk) {
                bn[kk] = *(const s8v*)(Bl + (size_t)nbN * 256 + kk * 32);
                acc0 = __builtin_amdgcn_mfma_f32_16x16x32_bf16(aR0[kk], bc[kk], acc0, 0, 0, 0);
                acc1 = __builtin_amdgcn_mfma_f32_16x16x32_bf16(aR1[kk], bc[kk], acc1, 0, 0, 0);
            }
            const int i = ti & 15;
            if (ti < 16) {   // slab sv
                const float4 c0 = *(const float4*)(sCsv + i * 64 + eb0);
                const float4 c1 = *(const float4*)(sCsv + i * 64 + eb1);
                pSV0[0] = fmaf(c0.x, acc0[0], pSV0[0]); pSV0[1] = fmaf(c0.y, acc0[1], pSV0[1]);
                pSV0[2] = fmaf(c0.z, acc0[2], pSV0[2]); pSV0[3] = fmaf(c0.w, acc0[3], pSV0[3]);
                pSV1[0] = fmaf(c1.x, acc1[0], pSV1[0]); pSV1[1] = fmaf(c1.y, acc1[1], pSV1[1]);
                pSV1[2] = fmaf(c1.z, acc1[2], pSV1[2]); pSV1[3] = fmaf(c1.w, acc1[3], pSV1[3]);
            } else {          // slab vs
                #pragma unroll
                for (int a = 0; a < 3; ++a) {
                    const float4 c0 = *(const float4*)(sCvs + (i * 3 + a) * 64 + eb0);
                    const float4 c1 = *(const float4*)(sCvs + (i * 3 + a) * 64 + eb1);
                    pVS0[a][0] = fmaf(c0.x, acc0[0], pVS0[a][0]);
                    pVS0[a][1] = fmaf(c0.y, acc0[1], pVS0[a][1]);
                    pVS0[a][2] = fmaf(c0.z, acc0[2], pVS0[a][2]);
                    pVS0[a][3] = fmaf(c0.w, acc0[3], pVS0[a][3]);
                    pVS1[a][0] = fmaf(c1.x, acc1[0], pVS1[a][0]);
                    pVS1[a][1] = fmaf(c1.y, acc1[1], pVS1[a][1]);
                    pVS1[a][2] = fmaf(c1.z, acc1[2], pVS1[a][2]);
                    pVS1[a][3] = fmaf(c1.w, acc1[3], pVS1[a][3]);
                }
            }
            #pragma unroll
            for (int kk = 0; kk < 8; ++kk) bc[kk] = bn[kk];
            bz = bzN;
        }
        // out_v[e][j][a] = y1[a][e]*pSV + pVS[a]   (scales folded in coefs)
        #pragma unroll
        for (int a = 0; a < 3; ++a) {
            const float4 y0q = *(const float4*)(sAttrT + (1 + a) * 64 + eb0);
            const float4 y1q = *(const float4*)(sAttrT + (1 + a) * 64 + eb1);
            #pragma unroll
            for (int q = 0; q < 4; ++q) {
                resV[(eb0 + q) * 48 + jj * 3 + a] =
                    fmaf(((const float*)&y0q)[q], pSV0[q], pVS0[a][q]);
                resV[(eb1 + q) * 48 + jj * 3 + a] =
                    fmaf(((const float*)&y1q)[q], pSV1[q], pVS1[a][q]);
            }
        }
    }
    __syncthreads();

    // ---------------- phase 4: coalesced store to F[e][64] ----------------
    {
        const int e = t >> 2, qq = t & 3;
        const int ge = e0 + e;
        if (ge < E) {
            float* fp = F + (size_t)ge * 64 + qq * 16;
            const float* rp = (qq == 0) ? (resS + e * 16) : (resV + e * 48 + (qq - 1) * 16);
            #pragma unroll
            for (int c = 0; c < 16; c += 4)
                *(float4*)(fp + c) = *(const float4*)(rp + c);
        }
    }
}

extern "C" void kernel_launch(void* const* d_in, const int* in_sizes, int n_in,
                              void* d_out, int out_size, void* d_ws, size_t ws_size,
                              hipStream_t stream)
{
    const float* node_features = (const float*)d_in[0];
    const float* edge_attr     = (const float*)d_in[1];
    const float* edge_emb      = (const float*)d_in[2];
    const float* W1            = (const float*)d_in[3];
    const float* b1            = (const float*)d_in[4];
    const float* W2            = (const float*)d_in[5];
    const float* b2            = (const float*)d_in[6];
    const int*   edge_src      = (const int*)d_in[7];
    const int*   edge_dst      = (const int*)d_in[8];
    float*       out           = (float*)d_out;

    const int E = in_sizes[7];
    const int N = out_size / 64;
    const float num_neigh = (float)E / (float)N;
    const float CC = 0.17677669529663689f / sqrtf(num_neigh);

    // ---- workspace layout ----
    char* ws = (char*)d_ws;
    size_t off = 0;
    auto alloc = [&](size_t bytes) { char* p = ws + off; off = (off + bytes + 255) & ~(size_t)255; return p; };
    ushort_t* W2bf   = (ushort_t*)alloc((size_t)1024 * 256 * 2);
    int*      counts = (int*)alloc((size_t)N * 4);
    int*      offs   = (int*)alloc((size_t)(N + 1) * 4);
    int*      cursor = (int*)alloc((size_t)N * 4);
    int*      elist  = (int*)alloc((size_t)E * 4);
    float*    F      = (float*)alloc((size_t)E * 64 * 4);
    (void)ws_size;

    hipMemsetAsync(counts, 0, (size_t)N * 4, stream);
    hipMemsetAsync(cursor, 0, (size_t)N * 4, stream);

    conv_w2<<<256, 256, 0, stream>>>(W2, W2bf);
    hist_kernel<<<(E + 255) / 256, 256, 0, stream>>>(edge_dst, counts, E);
    scan_kernel<<<1, 1024, 0, stream>>>(counts, offs, N);
    fill_kernel<<<(E + 255) / 256, 256, 0, stream>>>(edge_dst, offs, cursor, elist, E);

    const int blocks = (E + TE - 1) / TE;
    nequip_mfma<<<blocks, NTHR, 0, stream>>>(
        node_features, edge_attr, edge_emb, W1, b1, W2bf, b2,
        edge_src, F, E, CC);

    gather_kernel<<<(N + 3) / 4, 256, 0, stream>>>(F, offs, elist, out, N);
}